// Round 2
// baseline (25860.745 us; speedup 1.0000x reference)
//
#include <hip/hip_runtime.h>

// ---------------------------------------------------------------------------
// LSTM layer, T=512 B=64 D=H=1024, out = h_T (64x1024 fp32).
// Round 2: 256 blocks = 4 batch-groups x 64 col-slices (16 units each).
//   - Weights W,R slice in REGISTERS (64 x short8 = 256 VGPR, loop-invariant)
//   - x_t / h_t slices (32 KB each) staged via global_load_lds width=16 into
//     fragment-major LDS (chunk*1KB + lane*16B): conflict-free, DMA-ordered
//   - x staging double-buffered one step ahead (off the critical path)
//   - device barrier: one atomicAdd counter, one polling lane per block
// ---------------------------------------------------------------------------

typedef __attribute__((ext_vector_type(8))) short     short8;   // 8 bf16 (4 VGPR)
typedef __attribute__((ext_vector_type(4))) float     f32x4;
typedef __attribute__((ext_vector_type(8))) unsigned short ushort8v;
typedef __attribute__((ext_vector_type(4))) unsigned short ushort4v;

__device__ __forceinline__ unsigned short f2bf(float f) {
  unsigned int u = __float_as_uint(f);
  u += 0x7FFFu + ((u >> 16) & 1u);          // RNE
  return (unsigned short)(u >> 16);
}

__device__ __forceinline__ void dma16(const void* g, void* l) {
  __builtin_amdgcn_global_load_lds(
      (const __attribute__((address_space(1))) unsigned int*)g,
      (__attribute__((address_space(3))) unsigned int*)l, 16, 0, 0);
}

// ---------------- prep 1: cast x -> bf16; zero flags/counter ----------------
__global__ void k_cast_x(const float* __restrict__ x, unsigned short* __restrict__ xb,
                         int* __restrict__ flags) {
  long i = ((long)blockIdx.x * 256 + threadIdx.x) * 8;
  f32x4 a = *(const f32x4*)(x + i);
  f32x4 b = *(const f32x4*)(x + i + 4);
  ushort8v o;
  o[0] = f2bf(a[0]); o[1] = f2bf(a[1]); o[2] = f2bf(a[2]); o[3] = f2bf(a[3]);
  o[4] = f2bf(b[0]); o[5] = f2bf(b[1]); o[6] = f2bf(b[2]); o[7] = f2bf(b[3]);
  *(ushort8v*)(xb + i) = o;
  if (blockIdx.x == 0) flags[threadIdx.x] = 0;
}

// ---------------- prep 2: transpose-cast 1024x1024 fp32 -> dst[n][k] bf16 ---
__global__ void k_tcast(const float* __restrict__ src, unsigned short* __restrict__ dst) {
  __shared__ unsigned short tile[64][65];
  const int k0 = blockIdx.x << 6;
  const int n0 = blockIdx.y << 6;
  const int tid = threadIdx.x;
#pragma unroll
  for (int i = 0; i < 4; ++i) {
    int q = tid + (i << 8);
    int r = q >> 4, c4 = (q & 15) << 2;
    f32x4 v = *(const f32x4*)(src + (size_t)(k0 + r) * 1024 + n0 + c4);
    tile[r][c4 + 0] = f2bf(v[0]);
    tile[r][c4 + 1] = f2bf(v[1]);
    tile[r][c4 + 2] = f2bf(v[2]);
    tile[r][c4 + 3] = f2bf(v[3]);
  }
  __syncthreads();
#pragma unroll
  for (int i = 0; i < 4; ++i) {
    int q = tid + (i << 8);
    int rn = q >> 4, kc = (q & 15) << 2;
    ushort4v o;
    o[0] = tile[kc + 0][rn];
    o[1] = tile[kc + 1][rn];
    o[2] = tile[kc + 2][rn];
    o[3] = tile[kc + 3][rn];
    *(ushort4v*)(dst + (size_t)(n0 + rn) * 1024 + k0 + kc) = o;
  }
}

// ---------------- main: persistent recurrence -------------------------------
__global__ __launch_bounds__(256, 1) void k_lstm(
    const unsigned short* __restrict__ xb,    // [512*64][1024] bf16
    const unsigned short* __restrict__ WtT,   // [4096][1024] bf16, n = gate*1024+u
    const unsigned short* __restrict__ RtT,
    const float* __restrict__ b_i, const float* __restrict__ b_f,
    const float* __restrict__ b_o, const float* __restrict__ b_c,
    const float* __restrict__ s0, const float* __restrict__ c0,
    unsigned short* __restrict__ h_buf,       // [2][64*1024] bf16 double buffer
    int* __restrict__ counter, float* __restrict__ out) {
  // fragment-major staging: cell(kk, lane) at [kk*512 + lane*8] ushorts (1KB/chunk)
  __shared__ unsigned short Xs[2][16384];     // 2 x 32 KB: x_t slice, double-buffered
  __shared__ unsigned short Hs[16384];        // 32 KB: h_t slice
  __shared__ float gl[4 * 256];               // 4 KB: preactivation exchange

  const int tid = threadIdx.x;
  const int bid = blockIdx.x;                 // 256 blocks
  const int cs = bid & 63;                    // col slice -> units u0..u0+15
  const int bg = bid >> 6;                    // batch group -> rows b0..b0+15
  const int u0 = cs << 4;
  const int b0 = bg << 4;
  const int wv = tid >> 6;                    // wave = gate (0:i 1:f 2:o 3:c)
  const int ln = tid & 63;
  const int qd = ln >> 4;                     // quad (k sub-chunk)
  const int nc = ln & 15;                     // A: batch row idx / B: col idx

  // ---- one-time: weight fragments into registers (loop-invariant) ----
  short8 wf[32], rf[32];
  {
    const size_t nrow = ((size_t)wv << 10) + u0 + nc;   // gate*1024 + unit
    const unsigned short* wp = WtT + nrow * 1024 + (qd << 3);
    const unsigned short* rp = RtT + nrow * 1024 + (qd << 3);
#pragma unroll
    for (int kk = 0; kk < 32; ++kk) {
      wf[kk] = *(const short8*)(wp + kk * 32);
      rf[kk] = *(const short8*)(rp + kk * 32);
    }
  }

  // ---- per-thread state: (m = tid>>4, u = tid&15) ----
  const int m = tid >> 4;
  const int un = tid & 15;
  const int gi = (b0 + m) * 1024 + u0 + un;
  float c = c0[gi];
  const float bi = b_i[u0 + un], bf = b_f[u0 + un], bo = b_o[u0 + un], bc = b_c[u0 + un];

  // ---- publish h_0 = s0 (bf16), stage x_0, signal ----
  h_buf[gi] = f2bf(s0[gi]);
  {
    const unsigned short* gp = xb + (((size_t)(b0 + nc)) << 10) + (qd << 3);
#pragma unroll
    for (int j = 0; j < 8; ++j) {
      int kk = (wv << 3) + j;
      dma16(gp + kk * 32, &Xs[0][kk << 9]);
    }
  }
  __threadfence();
  __syncthreads();                            // drains DMA too
  if (tid == 0) __hip_atomic_fetch_add(counter, 1, __ATOMIC_RELEASE, __HIP_MEMORY_SCOPE_AGENT);

  for (int t = 0; t < 512; ++t) {
    // ---- x half (independent of other blocks; overlaps their step-t tail) ----
    f32x4 acc = {0.f, 0.f, 0.f, 0.f};
    const unsigned short* xsb = &Xs[t & 1][0];
#pragma unroll
    for (int kk = 0; kk < 32; ++kk) {
      short8 a = *(const short8*)(xsb + (kk << 9) + (ln << 3));
      acc = __builtin_amdgcn_mfma_f32_16x16x32_bf16(a, wf[kk], acc, 0, 0, 0);
    }
    // ---- wait for h_t from all blocks (one polling lane) ----
    if (tid == 0) {
      const int target = (t + 1) << 8;        // 256*(t+1)
      while (__hip_atomic_load(counter, __ATOMIC_RELAXED, __HIP_MEMORY_SCOPE_AGENT) < target)
        __builtin_amdgcn_s_sleep(1);
    }
    __syncthreads();
    __threadfence();                          // acquire: invalidate stale h lines
    // ---- stage h_t slice (32 KB, DMA, fragment-major) ----
    {
      const unsigned short* gp = h_buf + (((size_t)(t & 1)) << 16) +
                                 (((size_t)(b0 + nc)) << 10) + (qd << 3);
#pragma unroll
      for (int j = 0; j < 8; ++j) {
        int kk = (wv << 3) + j;
        dma16(gp + kk * 32, &Hs[kk << 9]);
      }
    }
    __syncthreads();                          // drain h DMA
    // ---- h half ----
#pragma unroll
    for (int kk = 0; kk < 32; ++kk) {
      short8 a = *(const short8*)(&Hs[0] + (kk << 9) + (ln << 3));
      acc = __builtin_amdgcn_mfma_f32_16x16x32_bf16(a, rf[kk], acc, 0, 0, 0);
    }
    // ---- exchange preacts (wave wv computed gate wv for 16x16 tile) ----
#pragma unroll
    for (int r = 0; r < 4; ++r)
      gl[(wv << 8) + ((qd << 2) + r) * 16 + nc] = acc[r];
    __syncthreads();
    // ---- prefetch x_{t+1} into the other Xs buffer (drains at loop-end sync) ----
    {
      int tn = (t + 1) & 511;
      const unsigned short* gp = xb + (((size_t)((tn << 6) + b0 + nc)) << 10) + (qd << 3);
#pragma unroll
      for (int j = 0; j < 8; ++j) {
        int kk = (wv << 3) + j;
        dma16(gp + kk * 32, &Xs[(t + 1) & 1][kk << 9]);
      }
    }
    // ---- gates (fp32), state update, publish h_{t+1} ----
    {
      float p_i = gl[0 * 256 + (m << 4) + un] + bi;
      float p_f = gl[1 * 256 + (m << 4) + un] + bf;
      float p_o = gl[2 * 256 + (m << 4) + un] + bo;
      float p_c = gl[3 * 256 + (m << 4) + un] + bc;
      float it = 0.5f * (tanhf(p_i) + 1.0f);
      float ft = 0.5f * (tanhf(p_f) + 1.0f);
      float ot = 0.5f * (tanhf(p_o) + 1.0f);
      float ch = tanhf(p_c);
      c = ft * c + it * ch;
      float h = ot * tanhf(c);
      h_buf[(((size_t)((t + 1) & 1)) << 16) + gi] = f2bf(h);
      if (t == 511) out[gi] = h;
    }
    __threadfence();                          // release h stores
    __syncthreads();                          // whole block done (drains x DMA too)
    if (tid == 0) __hip_atomic_fetch_add(counter, 1, __ATOMIC_RELEASE, __HIP_MEMORY_SCOPE_AGENT);
  }
}

// ---------------------------------------------------------------------------
extern "C" void kernel_launch(void* const* d_in, const int* in_sizes, int n_in,
                              void* d_out, int out_size, void* d_ws, size_t ws_size,
                              hipStream_t stream) {
  const float* x   = (const float*)d_in[0];
  const float* W_i = (const float*)d_in[1];
  const float* W_f = (const float*)d_in[2];
  const float* W_c = (const float*)d_in[3];
  const float* W_o = (const float*)d_in[4];
  const float* R_i = (const float*)d_in[5];
  const float* R_f = (const float*)d_in[6];
  const float* R_c = (const float*)d_in[7];
  const float* R_o = (const float*)d_in[8];
  const float* b_i = (const float*)d_in[9];
  const float* b_f = (const float*)d_in[10];
  const float* b_c = (const float*)d_in[11];
  const float* b_o = (const float*)d_in[12];
  const float* s0  = (const float*)d_in[13];
  const float* c0  = (const float*)d_in[14];
  float* out = (float*)d_out;

  char* ws = (char*)d_ws;
  unsigned short* xb   = (unsigned short*)(ws);                               // 64 MB
  unsigned short* WtT  = (unsigned short*)(ws + (size_t)67108864);            // 8 MB
  unsigned short* RtT  = (unsigned short*)(ws + (size_t)67108864 + 8388608);  // 8 MB
  unsigned short* hbuf = (unsigned short*)(ws + (size_t)67108864 + 16777216); // 256 KB
  int* flags           = (int*)(ws + (size_t)67108864 + 16777216 + 262144);

  k_cast_x<<<16384, 256, 0, stream>>>(x, xb, flags);
  // gate order i,f,o,c (wave index = gate)
  dim3 tg(16, 16);
  k_tcast<<<tg, 256, 0, stream>>>(W_i, WtT + 0);
  k_tcast<<<tg, 256, 0, stream>>>(W_f, WtT + 1048576);
  k_tcast<<<tg, 256, 0, stream>>>(W_o, WtT + 2097152);
  k_tcast<<<tg, 256, 0, stream>>>(W_c, WtT + 3145728);
  k_tcast<<<tg, 256, 0, stream>>>(R_i, RtT + 0);
  k_tcast<<<tg, 256, 0, stream>>>(R_f, RtT + 1048576);
  k_tcast<<<tg, 256, 0, stream>>>(R_o, RtT + 2097152);
  k_tcast<<<tg, 256, 0, stream>>>(R_c, RtT + 3145728);

  k_lstm<<<256, 256, 0, stream>>>(xb, WtT, RtT, b_i, b_f, b_o, b_c, s0, c0,
                                  hbuf, flags, out);
}

// Round 3
// 3332.636 us; speedup vs baseline: 7.7598x; 7.7598x over previous
//
#include <hip/hip_runtime.h>

// ---------------------------------------------------------------------------
// LSTM layer, T=512 B=64 D=H=1024, out = h_T (64x1024 fp32).
// Round 3: kill ALL per-step agent-scope cache maintenance (buffer_wbl2 /
// buffer_inv from __threadfence + acquire/release atomics were ~50us/step).
//   - h exchange via RELAXED agent atomics (sc0 sc1 -> LLC bypass, no fences)
//   - 4 independent sync domains (one per 16-row batch group, 64 blocks each),
//     8 padded sub-counters per domain (8 RMWs/line max)
//   - 512 thr/block: wave = (gate, k-half); weight frags 128 VGPR/thread
//     (no spill at launch_bounds(512,2)); 2 waves/SIMD
//   - x DMA prefetch issued before the poll (overlaps barrier wait)
// ---------------------------------------------------------------------------

typedef __attribute__((ext_vector_type(8))) short     short8;   // 8 bf16 (4 VGPR)
typedef __attribute__((ext_vector_type(4))) float     f32x4;
typedef __attribute__((ext_vector_type(8))) unsigned short ushort8v;
typedef __attribute__((ext_vector_type(4))) unsigned short ushort4v;
typedef __attribute__((ext_vector_type(4))) unsigned int   uint4v;

__device__ __forceinline__ unsigned short f2bf(float f) {
  unsigned int u = __float_as_uint(f);
  u += 0x7FFFu + ((u >> 16) & 1u);          // RNE
  return (unsigned short)(u >> 16);
}

__device__ __forceinline__ void dma16(const void* g, void* l) {
  __builtin_amdgcn_global_load_lds(
      (const __attribute__((address_space(1))) unsigned int*)g,
      (__attribute__((address_space(3))) unsigned int*)l, 16, 0, 0);
}

// ---------------- prep 1: cast x -> bf16; zero counters ---------------------
__global__ void k_cast_x(const float* __restrict__ x, unsigned short* __restrict__ xb,
                         int* __restrict__ flags) {
  long i = ((long)blockIdx.x * 256 + threadIdx.x) * 8;
  f32x4 a = *(const f32x4*)(x + i);
  f32x4 b = *(const f32x4*)(x + i + 4);
  ushort8v o;
  o[0] = f2bf(a[0]); o[1] = f2bf(a[1]); o[2] = f2bf(a[2]); o[3] = f2bf(a[3]);
  o[4] = f2bf(b[0]); o[5] = f2bf(b[1]); o[6] = f2bf(b[2]); o[7] = f2bf(b[3]);
  *(ushort8v*)(xb + i) = o;
  if (blockIdx.x < 4) flags[(blockIdx.x << 8) + threadIdx.x] = 0;   // 1024 ints
}

// ---------------- prep 2: transpose-cast 1024x1024 fp32 -> dst[n][k] bf16 ---
__global__ void k_tcast(const float* __restrict__ src, unsigned short* __restrict__ dst) {
  __shared__ unsigned short tile[64][65];
  const int k0 = blockIdx.x << 6;
  const int n0 = blockIdx.y << 6;
  const int tid = threadIdx.x;
#pragma unroll
  for (int i = 0; i < 4; ++i) {
    int q = tid + (i << 8);
    int r = q >> 4, c4 = (q & 15) << 2;
    f32x4 v = *(const f32x4*)(src + (size_t)(k0 + r) * 1024 + n0 + c4);
    tile[r][c4 + 0] = f2bf(v[0]);
    tile[r][c4 + 1] = f2bf(v[1]);
    tile[r][c4 + 2] = f2bf(v[2]);
    tile[r][c4 + 3] = f2bf(v[3]);
  }
  __syncthreads();
#pragma unroll
  for (int i = 0; i < 4; ++i) {
    int q = tid + (i << 8);
    int rn = q >> 4, kc = (q & 15) << 2;
    ushort4v o;
    o[0] = tile[kc + 0][rn];
    o[1] = tile[kc + 1][rn];
    o[2] = tile[kc + 2][rn];
    o[3] = tile[kc + 3][rn];
    *(ushort4v*)(dst + (size_t)(n0 + rn) * 1024 + k0 + kc) = o;
  }
}

// ---------------- main: persistent recurrence -------------------------------
__global__ __launch_bounds__(512, 2) void k_lstm(
    const unsigned short* __restrict__ xb,    // [512*64][1024] bf16
    const unsigned short* __restrict__ WtT,   // [4096][1024] bf16, n = gate*1024+u
    const unsigned short* __restrict__ RtT,
    const float* __restrict__ b_i, const float* __restrict__ b_f,
    const float* __restrict__ b_o, const float* __restrict__ b_c,
    const float* __restrict__ s0, const float* __restrict__ c0,
    unsigned short* __restrict__ h_buf,       // [4 groups][2][16*1024] bf16
    int* __restrict__ flags, float* __restrict__ out) {
  // fragment-major staging: cell(K, lane) at ushort [K*512 + lane*8]
  __shared__ unsigned short Xs[2][16384];     // 2 x 32 KB (x_t slice, dbuf)
  __shared__ unsigned short Hs[16384];        // 32 KB (h_t slice)
  __shared__ float gl[2048];                  // 8 KB: [khalf][gate][256]

  const int tid = threadIdx.x;
  const int bid = blockIdx.x;                 // 256 blocks = 4 bg x 64 cs
  const int cs = bid & 63;
  const int bg = bid >> 6;
  const int u0 = cs << 4;                     // 16 units
  const int b0 = bg << 4;                     // 16 batch rows
  const int wv = tid >> 6, ln = tid & 63;
  const int qd = ln >> 4, nc = ln & 15;
  const int gate = wv & 3;                    // 0:i 1:f 2:o 3:c
  const int kh = wv >> 2;                     // k-half
  const int hb = bg << 15;                    // group base in h_buf (ushort elems)

  // ---- weight fragments in registers: 32 x short8 = 128 VGPR ----
  short8 wf[16], rf[16];
  {
    const size_t nrow = ((size_t)gate << 10) + u0 + nc;
    const unsigned short* wp = WtT + nrow * 1024 + (kh << 9) + (qd << 3);
    const unsigned short* rp = RtT + nrow * 1024 + (kh << 9) + (qd << 3);
#pragma unroll
    for (int kk = 0; kk < 16; ++kk) {
      wf[kk] = *(const short8*)(wp + kk * 32);
      rf[kk] = *(const short8*)(rp + kk * 32);
    }
  }

  // ---- per-thread state (tid < 256): cell (m = tid>>4, un = tid&15) ----
  const int m = tid >> 4, un = tid & 15;
  const int gio = (b0 + m) * 1024 + u0 + un;  // global (batch,unit) index
  float c = 0.f, bi = 0.f, bf = 0.f, bo = 0.f, bc = 0.f;
  unsigned int* const hq = (unsigned int*)h_buf;
  if (tid < 256) {
    c = c0[gio];
    bi = b_i[u0 + un]; bf = b_f[u0 + un]; bo = b_o[u0 + un]; bc = b_c[u0 + un];
    float h0 = s0[gio];
    float hp = __shfl_xor(h0, 1);
    if ((tid & 1) == 0) {
      unsigned int w = (unsigned int)f2bf(h0) | ((unsigned int)f2bf(hp) << 16);
      __hip_atomic_store(&hq[(hb + m * 1024 + u0 + un) >> 1], w,
                         __ATOMIC_RELAXED, __HIP_MEMORY_SCOPE_AGENT);
    }
  }
  // ---- stage x_0 (4 chunks per wave) ----
#pragma unroll
  for (int j = 0; j < 4; ++j) {
    int K = (wv << 2) + j;
    dma16(xb + (((size_t)(b0 + nc)) << 10) + (K << 5) + (qd << 3), &Xs[0][K << 9]);
  }
  __syncthreads();                            // drains h0 stores (vmcnt) + DMA
  if (tid == 0)
    __hip_atomic_fetch_add(&flags[((bg << 3) + (bid & 7)) << 5], 1,
                           __ATOMIC_RELAXED, __HIP_MEMORY_SCOPE_AGENT);

  for (int t = 0; t < 512; ++t) {
    // ---- x half (independent of other blocks) ----
    f32x4 acc = {0.f, 0.f, 0.f, 0.f};
    {
      const unsigned short* xsb = &Xs[t & 1][kh << 13];
#pragma unroll
      for (int kk = 0; kk < 16; ++kk) {
        short8 a = *(const short8*)(xsb + (kk << 9) + (ln << 3));
        acc = __builtin_amdgcn_mfma_f32_16x16x32_bf16(a, wf[kk], acc, 0, 0, 0);
      }
    }
    // ---- prefetch x_{t+1} (overlaps the barrier wait) ----
    {
      int tn = (t + 1) & 511;
#pragma unroll
      for (int j = 0; j < 4; ++j) {
        int K = (wv << 2) + j;
        dma16(xb + (((size_t)((tn << 6) + b0 + nc)) << 10) + (K << 5) + (qd << 3),
              &Xs[(t + 1) & 1][K << 9]);
      }
    }
    // ---- group barrier: 8 sub-counters, relaxed (no cache maintenance) ----
    if (tid < 8) {
      int* cp = &flags[((bg << 3) + tid) << 5];
      const int target = (t + 1) << 3;
      while (__hip_atomic_load(cp, __ATOMIC_RELAXED, __HIP_MEMORY_SCOPE_AGENT) < target)
        __builtin_amdgcn_s_sleep(1);
    }
    __syncthreads();
    // ---- load h_t slice: relaxed agent uint loads (LLC) -> LDS frag layout --
    {
      const unsigned int* hgq = hq + ((hb + ((t & 1) << 14)) >> 1);
      unsigned int hv[16];
#pragma unroll
      for (int j = 0; j < 4; ++j) {
        int q = (j << 9) + tid, K = q >> 6, l2 = q & 63;
        int uidx = ((l2 & 15) << 9) + ((l2 >> 4) << 2) + (K << 4);
#pragma unroll
        for (int e = 0; e < 4; ++e)
          hv[(j << 2) + e] = __hip_atomic_load(hgq + uidx + e,
                                               __ATOMIC_RELAXED, __HIP_MEMORY_SCOPE_AGENT);
      }
#pragma unroll
      for (int j = 0; j < 4; ++j) {
        int q = (j << 9) + tid, K = q >> 6, l2 = q & 63;
        uint4v w = {hv[(j << 2) + 0], hv[(j << 2) + 1], hv[(j << 2) + 2], hv[(j << 2) + 3]};
        *((uint4v*)Hs + (K << 6) + l2) = w;
      }
    }
    __syncthreads();
    // ---- h half ----
    {
      const unsigned short* hsb = &Hs[kh << 13];
#pragma unroll
      for (int kk = 0; kk < 16; ++kk) {
        short8 a = *(const short8*)(hsb + (kk << 9) + (ln << 3));
        acc = __builtin_amdgcn_mfma_f32_16x16x32_bf16(a, rf[kk], acc, 0, 0, 0);
      }
    }
    // ---- exchange partial preacts: gl[kh][gate][m*16+nc] ----
    {
      float* glp = &gl[(kh << 10) + (gate << 8)];
#pragma unroll
      for (int r = 0; r < 4; ++r)
        glp[(((qd << 2) + r) << 4) + nc] = acc[r];
    }
    __syncthreads();
    // ---- gates, state update, publish h_{t+1} (relaxed atomic stores) ----
    if (tid < 256) {
      float p_i = gl[tid]        + gl[1024 + tid]        + bi;
      float p_f = gl[256 + tid]  + gl[1024 + 256 + tid]  + bf;
      float p_o = gl[512 + tid]  + gl[1024 + 512 + tid]  + bo;
      float p_c = gl[768 + tid]  + gl[1024 + 768 + tid]  + bc;
      float it = 0.5f * (tanhf(p_i) + 1.0f);
      float ft = 0.5f * (tanhf(p_f) + 1.0f);
      float ot = 0.5f * (tanhf(p_o) + 1.0f);
      float ch = tanhf(p_c);
      c = ft * c + it * ch;
      float h = ot * tanhf(c);
      float hp = __shfl_xor(h, 1);
      if ((tid & 1) == 0) {
        unsigned int w = (unsigned int)f2bf(h) | ((unsigned int)f2bf(hp) << 16);
        __hip_atomic_store(&hq[(hb + (((t + 1) & 1) << 14) + m * 1024 + u0 + un) >> 1], w,
                           __ATOMIC_RELAXED, __HIP_MEMORY_SCOPE_AGENT);
      }
      if (t == 511) out[gio] = h;
    }
    __syncthreads();                          // drains h stores (vmcnt) per wave
    if (tid == 0)
      __hip_atomic_fetch_add(&flags[((bg << 3) + (bid & 7)) << 5], 1,
                             __ATOMIC_RELAXED, __HIP_MEMORY_SCOPE_AGENT);
  }
}

// ---------------------------------------------------------------------------
extern "C" void kernel_launch(void* const* d_in, const int* in_sizes, int n_in,
                              void* d_out, int out_size, void* d_ws, size_t ws_size,
                              hipStream_t stream) {
  const float* x   = (const float*)d_in[0];
  const float* W_i = (const float*)d_in[1];
  const float* W_f = (const float*)d_in[2];
  const float* W_c = (const float*)d_in[3];
  const float* W_o = (const float*)d_in[4];
  const float* R_i = (const float*)d_in[5];
  const float* R_f = (const float*)d_in[6];
  const float* R_c = (const float*)d_in[7];
  const float* R_o = (const float*)d_in[8];
  const float* b_i = (const float*)d_in[9];
  const float* b_f = (const float*)d_in[10];
  const float* b_c = (const float*)d_in[11];
  const float* b_o = (const float*)d_in[12];
  const float* s0  = (const float*)d_in[13];
  const float* c0  = (const float*)d_in[14];
  float* out = (float*)d_out;

  char* ws = (char*)d_ws;
  unsigned short* xb   = (unsigned short*)(ws);                               // 64 MB
  unsigned short* WtT  = (unsigned short*)(ws + (size_t)67108864);            // 8 MB
  unsigned short* RtT  = (unsigned short*)(ws + (size_t)67108864 + 8388608);  // 8 MB
  unsigned short* hbuf = (unsigned short*)(ws + (size_t)67108864 + 16777216); // 256 KB
  int* flags           = (int*)(ws + (size_t)67108864 + 16777216 + 262144);

  k_cast_x<<<16384, 256, 0, stream>>>(x, xb, flags);
  // gate order i,f,o,c (wave gate index matches)
  dim3 tg(16, 16);
  k_tcast<<<tg, 256, 0, stream>>>(W_i, WtT + 0);
  k_tcast<<<tg, 256, 0, stream>>>(W_f, WtT + 1048576);
  k_tcast<<<tg, 256, 0, stream>>>(W_o, WtT + 2097152);
  k_tcast<<<tg, 256, 0, stream>>>(W_c, WtT + 3145728);
  k_tcast<<<tg, 256, 0, stream>>>(R_i, RtT + 0);
  k_tcast<<<tg, 256, 0, stream>>>(R_f, RtT + 1048576);
  k_tcast<<<tg, 256, 0, stream>>>(R_o, RtT + 2097152);
  k_tcast<<<tg, 256, 0, stream>>>(R_c, RtT + 3145728);

  k_lstm<<<256, 512, 0, stream>>>(xb, WtT, RtT, b_i, b_f, b_o, b_c, s0, c0,
                                  hbuf, flags, out);
}

// Round 4
// 1969.320 us; speedup vs baseline: 13.1318x; 1.6923x over previous
//
#include <hip/hip_runtime.h>

// ---------------------------------------------------------------------------
// LSTM layer, T=512 B=64 D=H=1024, out = h_T (64x1024 fp32).
// Round 4: fix the request-bound h-gather + 4x LDS fragment redundancy.
//   - h gather: coalesced global_load_dwordx4 sc0 sc1 (coherent via LLC),
//     XOR-swizzled ds_write_b128 into MFMA fragment layout (8 dw/bank = opt)
//   - wave = 4 K-chunks x ALL 4 gates (acc[4]); A-frags read once per chunk
//   - gates: fast sigma(2x) = rcp(1+exp(-2x)) (v_exp_f32), no libm tanh
//   - x-prefetch DMA by waves 4-7 overlaps gate math by waves 0-3
//   - barrier: relaxed agent atomics only (no L2 writeback/invalidate)
// ---------------------------------------------------------------------------

typedef __attribute__((ext_vector_type(8))) short     short8;   // 8 bf16 (4 VGPR)
typedef __attribute__((ext_vector_type(4))) float     f32x4;
typedef __attribute__((ext_vector_type(8))) unsigned short ushort8v;
typedef __attribute__((ext_vector_type(4))) unsigned short ushort4v;
typedef __attribute__((ext_vector_type(4))) unsigned int   uint4v;

__device__ __forceinline__ unsigned short f2bf(float f) {
  unsigned int u = __float_as_uint(f);
  u += 0x7FFFu + ((u >> 16) & 1u);          // RNE
  return (unsigned short)(u >> 16);
}

__device__ __forceinline__ void dma16(const void* g, void* l) {
  __builtin_amdgcn_global_load_lds(
      (const __attribute__((address_space(1))) unsigned int*)g,
      (__attribute__((address_space(3))) unsigned int*)l, 16, 0, 0);
}

__device__ __forceinline__ float sig2(float x) {   // = (tanh(x)+1)/2 = sigma(2x)
  return __builtin_amdgcn_rcpf(1.f + __expf(-2.f * x));
}

// ---------------- prep 1: cast x -> bf16; zero counters ---------------------
__global__ void k_cast_x(const float* __restrict__ x, unsigned short* __restrict__ xb,
                         int* __restrict__ flags) {
  long i = ((long)blockIdx.x * 256 + threadIdx.x) * 8;
  f32x4 a = *(const f32x4*)(x + i);
  f32x4 b = *(const f32x4*)(x + i + 4);
  ushort8v o;
  o[0] = f2bf(a[0]); o[1] = f2bf(a[1]); o[2] = f2bf(a[2]); o[3] = f2bf(a[3]);
  o[4] = f2bf(b[0]); o[5] = f2bf(b[1]); o[6] = f2bf(b[2]); o[7] = f2bf(b[3]);
  *(ushort8v*)(xb + i) = o;
  if (blockIdx.x < 4) flags[(blockIdx.x << 8) + threadIdx.x] = 0;   // 1024 ints
}

// ---------------- prep 2: transpose-cast 1024x1024 fp32 -> dst[n][k] bf16 ---
__global__ void k_tcast(const float* __restrict__ src, unsigned short* __restrict__ dst) {
  __shared__ unsigned short tile[64][65];
  const int k0 = blockIdx.x << 6;
  const int n0 = blockIdx.y << 6;
  const int tid = threadIdx.x;
#pragma unroll
  for (int i = 0; i < 4; ++i) {
    int q = tid + (i << 8);
    int r = q >> 4, c4 = (q & 15) << 2;
    f32x4 v = *(const f32x4*)(src + (size_t)(k0 + r) * 1024 + n0 + c4);
    tile[r][c4 + 0] = f2bf(v[0]);
    tile[r][c4 + 1] = f2bf(v[1]);
    tile[r][c4 + 2] = f2bf(v[2]);
    tile[r][c4 + 3] = f2bf(v[3]);
  }
  __syncthreads();
#pragma unroll
  for (int i = 0; i < 4; ++i) {
    int q = tid + (i << 8);
    int rn = q >> 4, kc = (q & 15) << 2;
    ushort4v o;
    o[0] = tile[kc + 0][rn];
    o[1] = tile[kc + 1][rn];
    o[2] = tile[kc + 2][rn];
    o[3] = tile[kc + 3][rn];
    *(ushort4v*)(dst + (size_t)(n0 + rn) * 1024 + k0 + kc) = o;
  }
}

// ---------------- main: persistent recurrence -------------------------------
__global__ __launch_bounds__(512, 2) void k_lstm(
    const unsigned short* __restrict__ xb,    // [512*64][1024] bf16
    const unsigned short* __restrict__ WtT,   // [4096][1024] bf16, n = gate*1024+u
    const unsigned short* __restrict__ RtT,
    const float* __restrict__ b_i, const float* __restrict__ b_f,
    const float* __restrict__ b_o, const float* __restrict__ b_c,
    const float* __restrict__ s0, const float* __restrict__ c0,
    unsigned short* __restrict__ h_buf,       // [4 groups][2][16*1024] bf16
    int* __restrict__ flags, float* __restrict__ out) {
  // x staging: cell(K, lane) at ushort [K*512 + lane*8] (DMA lane order)
  __shared__ __align__(16) unsigned short Xs[2][16384];   // 2 x 32 KB
  // h staging: SWIZZLED cell(K, qd, r) at ushort [K*512 + qd*128 + (r^(K&7))*8]
  __shared__ __align__(16) unsigned short Hs[16384];      // 32 KB
  __shared__ float gl[8192];                  // 32 KB: [wave][gate][m*16+un]

  const int tid = threadIdx.x;
  const int bid = blockIdx.x;                 // 256 blocks = 4 bg x 64 cs
  const int cs = bid & 63;
  const int bg = bid >> 6;
  const int u0 = cs << 4;                     // 16 units
  const int b0 = bg << 4;                     // 16 batch rows
  const int wv = tid >> 6, ln = tid & 63;
  const int qd = ln >> 4, nc = ln & 15;

  // ---- weights: wave wv owns chunks K = j4*8 + wv, ALL 4 gates ----
  // B-frag (gate,K): WtT[gate*1024 + u0 + nc][K*32 + qd*8 .. +7]
  short8 wfr[4][4], rfr[4][4];
#pragma unroll
  for (int j4 = 0; j4 < 4; ++j4) {
    const int K = (j4 << 3) + wv;
#pragma unroll
    for (int g = 0; g < 4; ++g) {
      const size_t off = ((size_t)((g << 10) + u0 + nc) << 10) + (K << 5) + (qd << 3);
      wfr[j4][g] = *(const short8*)(WtT + off);
      rfr[j4][g] = *(const short8*)(RtT + off);
    }
  }

  // ---- per-thread state (tid<256): cell (m = tid>>4, un = tid&15) ----
  const int m = tid >> 4, un = tid & 15;
  const int gio = (b0 + m) * 1024 + u0 + un;
  float c = 0.f, bi = 0.f, bff = 0.f, bo = 0.f, bc = 0.f;
  unsigned int* const hq = (unsigned int*)h_buf;
  if (tid < 256) {
    c = c0[gio];
    bi = b_i[u0 + un]; bff = b_f[u0 + un]; bo = b_o[u0 + un]; bc = b_c[u0 + un];
    float h0 = s0[gio];
    float hp = __shfl_xor(h0, 1);
    if (!(tid & 1)) {
      unsigned int wd = (unsigned int)f2bf(h0) | ((unsigned int)f2bf(hp) << 16);
      __hip_atomic_store(&hq[(bg << 14) + (m << 9) + ((u0 + un) >> 1)], wd,
                         __ATOMIC_RELAXED, __HIP_MEMORY_SCOPE_AGENT);
    }
  }
  // ---- stage x_0 (4 chunks per wave) ----
#pragma unroll
  for (int j = 0; j < 4; ++j) {
    int K = (wv << 2) + j;
    dma16(xb + (((size_t)(b0 + nc)) << 10) + (K << 5) + (qd << 3), &Xs[0][K << 9]);
  }
  __syncthreads();                            // drains h0 stores + x0 DMA
  if (tid == 0)
    __hip_atomic_fetch_add(&flags[((bg << 3) + (bid & 7)) << 5], 1,
                           __ATOMIC_RELAXED, __HIP_MEMORY_SCOPE_AGENT);

  // gather geometry (uniform per thread across steps)
  const int gr0 = tid >> 7;                   // row base 0..3
  const int gu8 = tid & 127;                  // 8-unit chunk index
  const int gK = gu8 >> 2, gq = gu8 & 3, gf = gK & 7;
  unsigned short* const gcell = &Hs[(gK << 9) + (gq << 7)];

  for (int t = 0; t < 512; ++t) {
    // ---- A: x half (no cross-block dependency) ----
    f32x4 acc[4] = {{0.f,0.f,0.f,0.f},{0.f,0.f,0.f,0.f},{0.f,0.f,0.f,0.f},{0.f,0.f,0.f,0.f}};
    {
      const unsigned short* xsb = &Xs[t & 1][0];
#pragma unroll
      for (int j4 = 0; j4 < 4; ++j4) {
        const int K = (j4 << 3) + wv;
        short8 a = *(const short8*)(xsb + (K << 9) + (ln << 3));
#pragma unroll
        for (int g = 0; g < 4; ++g)
          acc[g] = __builtin_amdgcn_mfma_f32_16x16x32_bf16(a, wfr[j4][g], acc[g], 0, 0, 0);
      }
    }
    // ---- B: group barrier (8 relaxed sub-counters) ----
    if (tid < 8) {
      int* cp = &flags[((bg << 3) + tid) << 5];
      const int target = (t + 1) << 3;
      while (__hip_atomic_load(cp, __ATOMIC_RELAXED, __HIP_MEMORY_SCOPE_AGENT) < target)
        __builtin_amdgcn_s_sleep(1);
    }
    __syncthreads();
    // ---- C: coalesced coherent gather of h_t -> swizzled Hs ----
    {
      const unsigned int* p0 = hq + (bg << 14) + ((t & 1) << 13) + (gr0 << 9) + (gu8 << 2);
      uint4v g0, g1, g2, g3;
      asm volatile(
          "global_load_dwordx4 %0, %4, off sc0 sc1\n\t"
          "global_load_dwordx4 %1, %5, off sc0 sc1\n\t"
          "global_load_dwordx4 %2, %6, off sc0 sc1\n\t"
          "global_load_dwordx4 %3, %7, off sc0 sc1\n\t"
          "s_waitcnt vmcnt(0)"
          : "=&v"(g0), "=&v"(g1), "=&v"(g2), "=&v"(g3)
          : "v"(p0), "v"(p0 + 2048), "v"(p0 + 4096), "v"(p0 + 6144)
          : "memory");
      *(uint4v*)(gcell + (((gr0 +  0) ^ gf) << 3)) = g0;
      *(uint4v*)(gcell + (((gr0 +  4) ^ gf) << 3)) = g1;
      *(uint4v*)(gcell + (((gr0 +  8) ^ gf) << 3)) = g2;
      *(uint4v*)(gcell + (((gr0 + 12) ^ gf) << 3)) = g3;
    }
    __syncthreads();
    // ---- D: h half (swizzled A-frag reads) ----
    {
#pragma unroll
      for (int j4 = 0; j4 < 4; ++j4) {
        const int K = (j4 << 3) + wv;
        short8 a = *(const short8*)(&Hs[(K << 9) + (qd << 7) + (((nc ^ (K & 7))) << 3)]);
#pragma unroll
        for (int g = 0; g < 4; ++g)
          acc[g] = __builtin_amdgcn_mfma_f32_16x16x32_bf16(a, rfr[j4][g], acc[g], 0, 0, 0);
      }
      // gl[wv][gate][(qd*4+rr)*16 + nc]
      float* glw = &gl[(wv << 10)];
#pragma unroll
      for (int g = 0; g < 4; ++g)
#pragma unroll
        for (int rr = 0; rr < 4; ++rr)
          glw[(g << 8) + (((qd << 2) + rr) << 4) + nc] = acc[g][rr];
    }
    __syncthreads();
    // ---- F: gates (waves 0-3) / x prefetch (waves 4-7) ----
    if (tid < 256) {
      float pi = bi, pf = bff, po = bo, pc = bc;
#pragma unroll
      for (int w = 0; w < 8; ++w) {
        const float* glr = &gl[(w << 10) + tid];
        pi += glr[0]; pf += glr[256]; po += glr[512]; pc += glr[768];
      }
      float it = sig2(pi), ft = sig2(pf), ot = sig2(po);
      float ch = 2.f * sig2(pc) - 1.f;
      c = ft * c + it * ch;
      float h = ot * (2.f * sig2(c) - 1.f);
      float hp = __shfl_xor(h, 1);
      if (!(tid & 1)) {
        unsigned int wd = (unsigned int)f2bf(h) | ((unsigned int)f2bf(hp) << 16);
        __hip_atomic_store(&hq[(bg << 14) + (((t + 1) & 1) << 13) + (m << 9) + ((u0 + un) >> 1)],
                           wd, __ATOMIC_RELAXED, __HIP_MEMORY_SCOPE_AGENT);
      }
      if (t == 511) out[gio] = h;
    } else {
      // waves 4-7: stage x_{t+1} (8 chunks each)
      const int tn = (t + 1) & 511;
      const unsigned short* gp = xb + (((size_t)((tn << 6) + b0 + nc)) << 10) + (qd << 3);
      unsigned short* xd = &Xs[(t + 1) & 1][0];
#pragma unroll
      for (int j = 0; j < 8; ++j) {
        int K = ((wv & 3) << 3) + j;
        dma16(gp + (K << 5), xd + (K << 9));
      }
    }
    __syncthreads();                          // drains h stores (vmcnt) + x DMA
    if (tid == 0)
      __hip_atomic_fetch_add(&flags[((bg << 3) + (bid & 7)) << 5], 1,
                             __ATOMIC_RELAXED, __HIP_MEMORY_SCOPE_AGENT);
  }
}

// ---------------------------------------------------------------------------
extern "C" void kernel_launch(void* const* d_in, const int* in_sizes, int n_in,
                              void* d_out, int out_size, void* d_ws, size_t ws_size,
                              hipStream_t stream) {
  const float* x   = (const float*)d_in[0];
  const float* W_i = (const float*)d_in[1];
  const float* W_f = (const float*)d_in[2];
  const float* W_c = (const float*)d_in[3];
  const float* W_o = (const float*)d_in[4];
  const float* R_i = (const float*)d_in[5];
  const float* R_f = (const float*)d_in[6];
  const float* R_c = (const float*)d_in[7];
  const float* R_o = (const float*)d_in[8];
  const float* b_i = (const float*)d_in[9];
  const float* b_f = (const float*)d_in[10];
  const float* b_c = (const float*)d_in[11];
  const float* b_o = (const float*)d_in[12];
  const float* s0  = (const float*)d_in[13];
  const float* c0  = (const float*)d_in[14];
  float* out = (float*)d_out;

  char* ws = (char*)d_ws;
  unsigned short* xb   = (unsigned short*)(ws);                               // 64 MB
  unsigned short* WtT  = (unsigned short*)(ws + (size_t)67108864);            // 8 MB
  unsigned short* RtT  = (unsigned short*)(ws + (size_t)67108864 + 8388608);  // 8 MB
  unsigned short* hbuf = (unsigned short*)(ws + (size_t)67108864 + 16777216); // 256 KB
  int* flags           = (int*)(ws + (size_t)67108864 + 16777216 + 262144);

  k_cast_x<<<16384, 256, 0, stream>>>(x, xb, flags);
  // gate order i,f,o,c
  dim3 tg(16, 16);
  k_tcast<<<tg, 256, 0, stream>>>(W_i, WtT + 0);
  k_tcast<<<tg, 256, 0, stream>>>(W_f, WtT + 1048576);
  k_tcast<<<tg, 256, 0, stream>>>(W_o, WtT + 2097152);
  k_tcast<<<tg, 256, 0, stream>>>(W_c, WtT + 3145728);
  k_tcast<<<tg, 256, 0, stream>>>(R_i, RtT + 0);
  k_tcast<<<tg, 256, 0, stream>>>(R_f, RtT + 1048576);
  k_tcast<<<tg, 256, 0, stream>>>(R_o, RtT + 2097152);
  k_tcast<<<tg, 256, 0, stream>>>(R_c, RtT + 3145728);

  k_lstm<<<256, 512, 0, stream>>>(xb, WtT, RtT, b_i, b_f, b_o, b_c, s0, c0,
                                  hbuf, flags, out);
}

// Round 5
// 1424.761 us; speedup vs baseline: 18.1509x; 1.3822x over previous
//
#include <hip/hip_runtime.h>

// ---------------------------------------------------------------------------
// LSTM layer, T=512 B=64 D=H=1024, out = h_T (64x1024 fp32).
// Round 5: compress the per-step serial chain.
//   - wave-private K-chunks (K = wv+8*j4) for BOTH Xs and Hs: poll, gather,
//     Hs write, h-MFMA are per-wave (no block barrier on the critical path;
//     only 2 __syncthreads/step: gl exchange + h-store drain)
//   - x-DMA for t+1 issued right after x-MFMA -> drains during poll wait,
//     NOT between h-store and flag add (round-4 bug)
//   - correct XOR swizzle sub' = sub^(row&3): conflict-free b128 writes,
//     2-way (free) b128 reads  [round-4 swizzle was 4-way on writes]
//   - h exchange & flags: relaxed agent atomics (sc0 sc1, no L2 maintenance)
// ---------------------------------------------------------------------------

typedef __attribute__((ext_vector_type(8))) short     short8;   // 8 bf16 (4 VGPR)
typedef __attribute__((ext_vector_type(4))) float     f32x4;
typedef __attribute__((ext_vector_type(8))) unsigned short ushort8v;
typedef __attribute__((ext_vector_type(4))) unsigned short ushort4v;
typedef __attribute__((ext_vector_type(4))) unsigned int   uint4v;

__device__ __forceinline__ unsigned short f2bf(float f) {
  unsigned int u = __float_as_uint(f);
  u += 0x7FFFu + ((u >> 16) & 1u);          // RNE
  return (unsigned short)(u >> 16);
}

__device__ __forceinline__ void dma16(const void* g, void* l) {
  __builtin_amdgcn_global_load_lds(
      (const __attribute__((address_space(1))) unsigned int*)g,
      (__attribute__((address_space(3))) unsigned int*)l, 16, 0, 0);
}

__device__ __forceinline__ float sig2(float x) {   // = (tanh(x)+1)/2 = sigma(2x)
  return __builtin_amdgcn_rcpf(1.f + __expf(-2.f * x));
}

// ---------------- prep 1: cast x -> bf16; zero counters ---------------------
__global__ void k_cast_x(const float* __restrict__ x, unsigned short* __restrict__ xb,
                         int* __restrict__ flags) {
  long i = ((long)blockIdx.x * 256 + threadIdx.x) * 8;
  f32x4 a = *(const f32x4*)(x + i);
  f32x4 b = *(const f32x4*)(x + i + 4);
  ushort8v o;
  o[0] = f2bf(a[0]); o[1] = f2bf(a[1]); o[2] = f2bf(a[2]); o[3] = f2bf(a[3]);
  o[4] = f2bf(b[0]); o[5] = f2bf(b[1]); o[6] = f2bf(b[2]); o[7] = f2bf(b[3]);
  *(ushort8v*)(xb + i) = o;
  if (blockIdx.x < 4) flags[(blockIdx.x << 8) + threadIdx.x] = 0;   // 1024 ints
}

// ---------------- prep 2: transpose-cast 8 x (1024x1024 fp32 -> [n][k] bf16)
__global__ void k_tcast8(const float* __restrict__ s0, const float* __restrict__ s1,
                         const float* __restrict__ s2, const float* __restrict__ s3,
                         const float* __restrict__ s4, const float* __restrict__ s5,
                         const float* __restrict__ s6, const float* __restrict__ s7,
                         unsigned short* __restrict__ dstBase) {
  __shared__ unsigned short tile[64][65];
  const int z = blockIdx.z;
  const float* src = (z == 0) ? s0 : (z == 1) ? s1 : (z == 2) ? s2 : (z == 3) ? s3
                   : (z == 4) ? s4 : (z == 5) ? s5 : (z == 6) ? s6 : s7;
  unsigned short* dst = dstBase + (size_t)z * 1048576;
  const int k0 = blockIdx.x << 6;
  const int n0 = blockIdx.y << 6;
  const int tid = threadIdx.x;
#pragma unroll
  for (int i = 0; i < 4; ++i) {
    int q = tid + (i << 8);
    int r = q >> 4, c4 = (q & 15) << 2;
    f32x4 v = *(const f32x4*)(src + (size_t)(k0 + r) * 1024 + n0 + c4);
    tile[r][c4 + 0] = f2bf(v[0]);
    tile[r][c4 + 1] = f2bf(v[1]);
    tile[r][c4 + 2] = f2bf(v[2]);
    tile[r][c4 + 3] = f2bf(v[3]);
  }
  __syncthreads();
#pragma unroll
  for (int i = 0; i < 4; ++i) {
    int q = tid + (i << 8);
    int rn = q >> 4, kc = (q & 15) << 2;
    ushort4v o;
    o[0] = tile[kc + 0][rn];
    o[1] = tile[kc + 1][rn];
    o[2] = tile[kc + 2][rn];
    o[3] = tile[kc + 3][rn];
    *(ushort4v*)(dst + (size_t)(n0 + rn) * 1024 + k0 + kc) = o;
  }
}

// ---------------- main: persistent recurrence -------------------------------
__global__ __launch_bounds__(512, 2) void k_lstm(
    const unsigned short* __restrict__ xb,    // [512*64][1024] bf16
    const unsigned short* __restrict__ WtT,   // [4096][1024] bf16, n = gate*1024+u
    const unsigned short* __restrict__ RtT,
    const float* __restrict__ b_i, const float* __restrict__ b_f,
    const float* __restrict__ b_o, const float* __restrict__ b_c,
    const float* __restrict__ s0, const float* __restrict__ c0,
    unsigned short* __restrict__ h_buf,       // [4 groups][2][16*1024] bf16
    int* __restrict__ flags, float* __restrict__ out) {
  // chunk K (=32 k-dims) layout: [K][row 0..15][sub' 0..3] of 16B cells,
  // sub' = sub ^ (row&3); chunk = 1 KB. Wave wv owns K in {wv, wv+8, wv+16, wv+24}.
  __shared__ __align__(16) unsigned short Xs[2][16384];   // 2 x 32 KB
  __shared__ __align__(16) unsigned short Hs[16384];      // 32 KB
  __shared__ float gl[8192];                  // 32 KB: [wave][gate][m*16+un]

  const int tid = threadIdx.x;
  const int bid = blockIdx.x;                 // 256 blocks = 4 bg x 64 cs
  const int cs = bid & 63;
  const int bg = bid >> 6;
  const int u0 = cs << 4;                     // 16 units
  const int b0 = bg << 4;                     // 16 batch rows
  const int wv = tid >> 6, ln = tid & 63;
  const int qd = ln >> 4, nc = ln & 15;
  const int grow = ln >> 2;                   // 0..15 (row for gather/DMA)
  const int gsub = ln & 3;                    // 0..3  (global octet)
  const int gsx = gsub ^ (grow & 3);          // swizzled slot / swizzled octet

  // ---- weights: wave wv owns chunks K = j4*8 + wv, ALL 4 gates ----
  short8 wfr[4][4], rfr[4][4];
#pragma unroll
  for (int j4 = 0; j4 < 4; ++j4) {
    const int K = (j4 << 3) + wv;
#pragma unroll
    for (int g = 0; g < 4; ++g) {
      const size_t off = ((size_t)((g << 10) + u0 + nc) << 10) + (K << 5) + (qd << 3);
      wfr[j4][g] = *(const short8*)(WtT + off);
      rfr[j4][g] = *(const short8*)(RtT + off);
    }
  }

  // ---- per-thread state (tid<256): cell (m, un) ----
  const int m = tid >> 4, un = tid & 15;
  const int gio = (b0 + m) * 1024 + u0 + un;
  float c = 0.f, bi = 0.f, bff = 0.f, bo = 0.f, bc = 0.f;
  unsigned int* const hq = (unsigned int*)h_buf;
  const int hq_bg = bg << 14;                 // dword base of this group's region
  if (tid < 256) {
    c = c0[gio];
    bi = b_i[u0 + un]; bff = b_f[u0 + un]; bo = b_o[u0 + un]; bc = b_c[u0 + un];
    float h0 = s0[gio];
    float hp = __shfl_xor(h0, 1);
    if (!(tid & 1)) {
      unsigned int wd = (unsigned int)f2bf(h0) | ((unsigned int)f2bf(hp) << 16);
      __hip_atomic_store(&hq[hq_bg + (m << 9) + ((u0 + un) >> 1)], wd,
                         __ATOMIC_RELAXED, __HIP_MEMORY_SCOPE_AGENT);
    }
  }
  // ---- stage x_0 (wave-private chunks; lds base is wave-uniform) ----
#pragma unroll
  for (int j4 = 0; j4 < 4; ++j4) {
    const int K = (j4 << 3) + wv;
    dma16(xb + (((size_t)(b0 + grow)) << 10) + (K << 5) + (gsx << 3), &Xs[0][K << 9]);
  }
  __syncthreads();                            // drains h0 stores + x0 DMA
  if (tid == 0)
    __hip_atomic_fetch_add(&flags[((bg << 3) + (bid & 7)) << 5], 1,
                           __ATOMIC_RELAXED, __HIP_MEMORY_SCOPE_AGENT);

  for (int t = 0; t < 512; ++t) {
    f32x4 acc[4] = {{0.f,0.f,0.f,0.f},{0.f,0.f,0.f,0.f},{0.f,0.f,0.f,0.f},{0.f,0.f,0.f,0.f}};
    // ---- x half (wave-private chunks) ----
    {
      const unsigned short* xsb = &Xs[t & 1][0];
#pragma unroll
      for (int j4 = 0; j4 < 4; ++j4) {
        const int K = (j4 << 3) + wv;
        short8 a = *(const short8*)(xsb + (K << 9) + (nc << 5) + ((qd ^ (nc & 3)) << 3));
#pragma unroll
        for (int g = 0; g < 4; ++g)
          acc[g] = __builtin_amdgcn_mfma_f32_16x16x32_bf16(a, wfr[j4][g], acc[g], 0, 0, 0);
      }
    }
    // ---- issue x_{t+1} DMA now: drains during the poll, off the signal path --
    {
      const int tn = (t + 1) & 511;
      const size_t xrow = (size_t)((tn << 6) + b0 + grow) << 10;
      unsigned short* xd = &Xs[(t + 1) & 1][0];
#pragma unroll
      for (int j4 = 0; j4 < 4; ++j4) {
        const int K = (j4 << 3) + wv;
        dma16(xb + xrow + (K << 5) + (gsx << 3), xd + (K << 9));
      }
    }
    // ---- per-wave poll: lane ln spins on sub-counter ln&7 ----
    {
      int* cp = &flags[((bg << 3) + (ln & 7)) << 5];
      const int target = (t + 1) << 3;
      while (__hip_atomic_load(cp, __ATOMIC_RELAXED, __HIP_MEMORY_SCOPE_AGENT) < target)
        __builtin_amdgcn_s_sleep(1);
    }
    // ---- per-wave gather of own chunks (coherent dwordx4) -> swizzled Hs ----
    {
      const unsigned int* pb = hq + hq_bg + ((t & 1) << 13) + (grow << 9) + (gsub << 2);
      uint4v g0, g1, g2, g3;
      asm volatile(
          "global_load_dwordx4 %0, %4, off sc0 sc1\n\t"
          "global_load_dwordx4 %1, %5, off sc0 sc1\n\t"
          "global_load_dwordx4 %2, %6, off sc0 sc1\n\t"
          "global_load_dwordx4 %3, %7, off sc0 sc1\n\t"
          "s_waitcnt vmcnt(0)"
          : "=&v"(g0), "=&v"(g1), "=&v"(g2), "=&v"(g3)
          : "v"(pb + (wv << 4)), "v"(pb + ((8 + wv) << 4)),
            "v"(pb + ((16 + wv) << 4)), "v"(pb + ((24 + wv) << 4))
          : "memory");
      unsigned short* hdst = &Hs[(grow << 5) + (gsx << 3)];
      *(uint4v*)(hdst + (wv << 9)) = g0;
      *(uint4v*)(hdst + ((8 + wv) << 9)) = g1;
      *(uint4v*)(hdst + ((16 + wv) << 9)) = g2;
      *(uint4v*)(hdst + ((24 + wv) << 9)) = g3;
    }
    // ---- h half (same wave-private chunks; no barrier needed) ----
    {
#pragma unroll
      for (int j4 = 0; j4 < 4; ++j4) {
        const int K = (j4 << 3) + wv;
        short8 a = *(const short8*)(&Hs[(K << 9) + (nc << 5) + ((qd ^ (nc & 3)) << 3)]);
#pragma unroll
        for (int g = 0; g < 4; ++g)
          acc[g] = __builtin_amdgcn_mfma_f32_16x16x32_bf16(a, rfr[j4][g], acc[g], 0, 0, 0);
      }
      float* glw = &gl[wv << 10];
#pragma unroll
      for (int g = 0; g < 4; ++g)
#pragma unroll
        for (int rr = 0; rr < 4; ++rr)
          glw[(g << 8) + (((qd << 2) + rr) << 4) + nc] = acc[g][rr];
    }
    __syncthreads();                          // gl ready (syncA)
    // ---- gates, state update, publish h_{t+1} ----
    if (tid < 256) {
      float pi = bi, pf = bff, po = bo, pc = bc;
#pragma unroll
      for (int w = 0; w < 8; ++w) {
        const float* glr = &gl[(w << 10) + tid];
        pi += glr[0]; pf += glr[256]; po += glr[512]; pc += glr[768];
      }
      float it = sig2(pi), ft = sig2(pf), ot = sig2(po);
      float ch = 2.f * sig2(pc) - 1.f;
      c = ft * c + it * ch;
      float h = ot * (2.f * sig2(c) - 1.f);
      float hp = __shfl_xor(h, 1);
      if (!(tid & 1)) {
        unsigned int wd = (unsigned int)f2bf(h) | ((unsigned int)f2bf(hp) << 16);
        __hip_atomic_store(&hq[hq_bg + (((t + 1) & 1) << 13) + (m << 9) + ((u0 + un) >> 1)],
                           wd, __ATOMIC_RELAXED, __HIP_MEMORY_SCOPE_AGENT);
      }
      if (t == 511) out[gio] = h;
    }
    __syncthreads();                          // h stores drained (syncB)
    if (tid == 0)
      __hip_atomic_fetch_add(&flags[((bg << 3) + (bid & 7)) << 5], 1,
                             __ATOMIC_RELAXED, __HIP_MEMORY_SCOPE_AGENT);
  }
}

// ---------------------------------------------------------------------------
extern "C" void kernel_launch(void* const* d_in, const int* in_sizes, int n_in,
                              void* d_out, int out_size, void* d_ws, size_t ws_size,
                              hipStream_t stream) {
  const float* x   = (const float*)d_in[0];
  const float* W_i = (const float*)d_in[1];
  const float* W_f = (const float*)d_in[2];
  const float* W_c = (const float*)d_in[3];
  const float* W_o = (const float*)d_in[4];
  const float* R_i = (const float*)d_in[5];
  const float* R_f = (const float*)d_in[6];
  const float* R_c = (const float*)d_in[7];
  const float* R_o = (const float*)d_in[8];
  const float* b_i = (const float*)d_in[9];
  const float* b_f = (const float*)d_in[10];
  const float* b_c = (const float*)d_in[11];
  const float* b_o = (const float*)d_in[12];
  const float* s0  = (const float*)d_in[13];
  const float* c0  = (const float*)d_in[14];
  float* out = (float*)d_out;

  char* ws = (char*)d_ws;
  unsigned short* xb   = (unsigned short*)(ws);                               // 64 MB
  unsigned short* WtT  = (unsigned short*)(ws + (size_t)67108864);            // 8 MB
  unsigned short* RtT  = (unsigned short*)(ws + (size_t)67108864 + 8388608);  // 8 MB (contiguous after WtT)
  unsigned short* hbuf = (unsigned short*)(ws + (size_t)67108864 + 16777216); // 256 KB
  int* flags           = (int*)(ws + (size_t)67108864 + 16777216 + 262144);

  k_cast_x<<<16384, 256, 0, stream>>>(x, xb, flags);
  // gate order i,f,o,c; z 0..3 -> W into WtT, z 4..7 -> R into RtT (contiguous)
  dim3 tg(16, 16, 8);
  k_tcast8<<<tg, 256, 0, stream>>>(W_i, W_f, W_o, W_c, R_i, R_f, R_o, R_c, WtT);

  k_lstm<<<256, 512, 0, stream>>>(xb, WtT, RtT, b_i, b_f, b_o, b_c, s0, c0,
                                  hbuf, flags, out);
}